// Round 1
// baseline (657.288 us; speedup 1.0000x reference)
//
#include <hip/hip_runtime.h>
#include <hip/hip_bf16.h>

#define NG 32
#define NH 16
#define NR 15
#define HS 256
#define NT 1000
#define NS 2000
#define LOUT (NT - NR + 1)  // 986
#define TC 40               // scan time-chunk

__device__ __forceinline__ float fast_rcp(float x) { return __builtin_amdgcn_rcpf(x); }
__device__ __forceinline__ float fast_tanh(float x) {
    float e = __expf(2.0f * x);
    return 1.0f - 2.0f * fast_rcp(e + 1.0f);
}
__device__ __forceinline__ float fast_sigmoid(float x) {
    return fast_rcp(1.0f + __expf(-x));
}

// ---------------------------------------------------------------------------
// Kernel 1: per-site parameters. One block per site, 256 threads (= HS).
// ---------------------------------------------------------------------------
__global__ __launch_bounds__(256) void k_site(
    const float* __restrict__ xc, const float* __restrict__ W_fc, const float* __restrict__ b_fc,
    const float* __restrict__ W_r, const float* __restrict__ b_r,
    const float* __restrict__ W_g, const float* __restrict__ b_g,
    const float* __restrict__ b_kin,
    float* __restrict__ state2, float* __restrict__ params, float* __restrict__ wfir)
{
    int s = blockIdx.x, tid = threadIdx.x;
    __shared__ float sXc[NG];
    __shared__ float sG[HS];
    __shared__ float sPG[144];
    __shared__ float sPR[256];
    if (tid < NG) sXc[tid] = xc[s * NG + tid];
    __syncthreads();
    // state[u] = b_fc[u] + sum_g xc[g]*W_fc[g][u]
    float st = b_fc[tid];
#pragma unroll
    for (int g = 0; g < NG; ++g) st += sXc[g] * W_fc[g * HS + tid];
    state2[s * HS + tid] = st + b_kin[tid];
    float gv = fast_tanh(st);
    sG[tid] = gv;
    __syncthreads();
    // pR: 256 outputs
    {
        float a = b_r[tid];
#pragma unroll 8
        for (int u = 0; u < HS; ++u) a += sG[u] * W_r[u * 256 + tid];
        sPR[tid] = a;
    }
    // pG: 144 outputs
    if (tid < 144) {
        float a = b_g[tid];
#pragma unroll 8
        for (int u = 0; u < HS; ++u) a += sG[u] * W_g[u * 144 + tid];
        sPG[tid] = a;
    }
    __syncthreads();
    if (tid < NH) {
        int h = tid;
        // ga softmax over 16 heads (each thread independent, reads LDS)
        float m = -1e30f;
        for (int k = 0; k < NH; ++k) m = fmaxf(m, sPG[96 + k]);
        float sum = 0.f;
        for (int k = 0; k < NH; ++k) sum += __expf(sPG[96 + k] - m);
        float ga = __expf(sPG[96 + h] - m) * fast_rcp(sum);
        float kp = fast_sigmoid(sPG[h]);
        float ks = fast_sigmoid(sPG[16 + h]);
        float kd = fast_sigmoid(sPG[32 + h]);
        float gd = fast_sigmoid(sPG[48 + h]);
        float glv = fast_sigmoid(sPG[64 + h]) * 10.0f;
        float gl = glv * glv * glv;
        float qb = fmaxf(sPG[80 + h], 0.f) * 0.1f;
        float gi = fminf(fmaxf(sPG[112 + h] * (1.0f / 6.0f) + 0.5f, 0.f), 1.f) * 0.5f;
        float ge = fmaxf(sPG[128 + h], 0.f);
        float* P = params + s * 128;
        P[0 * 16 + h] = kp;  P[1 * 16 + h] = ks;  P[2 * 16 + h] = kd;  P[3 * 16 + h] = gd;
        P[4 * 16 + h] = gl;  P[5 * 16 + h] = qb;  P[6 * 16 + h] = gi;  P[7 * 16 + h] = ge;
        // routing weights: softmax over 15 lags, scaled by ga
        float loc = fast_sigmoid(sPR[h * 16 + 0]) * 15.0f;
        float l[NR];
        float mm = -1e30f;
#pragma unroll
        for (int i = 0; i < NR; ++i) {
            float d = (float)i - loc;
            l[i] = sPR[h * 16 + 1 + i] - d * d;
            mm = fmaxf(mm, l[i]);
        }
        float ssum = 0.f;
#pragma unroll
        for (int i = 0; i < NR; ++i) { l[i] = __expf(l[i] - mm); ssum += l[i]; }
        float r = fast_rcp(ssum) * ga;
#pragma unroll
        for (int i = 0; i < NR; ++i) wfir[s * (NR * NH) + i * NH + h] = l[i] * r;
    }
}

// ---------------------------------------------------------------------------
// Kernel 2: km[t,s,h] = exp(tanh(state2 + f·W_kin) @ W_kout + b_kout)
// plus forcing precompute (Ps, Pl, Ev) transposed to [s][t].
// One block per site; threads over t. All weights broadcast from LDS.
// ---------------------------------------------------------------------------
__global__ __launch_bounds__(256) void k_km(
    const float* __restrict__ x, const float* __restrict__ state2,
    const float* __restrict__ W_kin, const float* __restrict__ W_kout,
    const float* __restrict__ b_kout,
    float* __restrict__ kmqt, float* __restrict__ psplev)
{
    int s = blockIdx.x, tid = threadIdx.x;
    __shared__ float sSt[HS];
    __shared__ float sWk[4][HS];
    __shared__ float sWo[HS * NH];
    __shared__ float sBo[NH];
    sSt[tid] = state2[s * HS + tid];
#pragma unroll
    for (int c = 0; c < 4; ++c) sWk[c][tid] = W_kin[c * HS + tid];
    {
        const float4* w4 = (const float4*)W_kout;
        float4* d4 = (float4*)sWo;
#pragma unroll
        for (int c = 0; c < 4; ++c) d4[tid + 256 * c] = w4[tid + 256 * c];
    }
    if (tid < NH) sBo[tid] = b_kout[tid];
    __syncthreads();
    for (int t = tid; t < NT; t += 256) {
        const float* xp = x + ((size_t)t * NS + s) * 6;
        float p0 = xp[0], p1 = xp[1], f0 = xp[2], f1 = xp[3], f2 = xp[4], f3 = xp[5];
        float acc[NH];
#pragma unroll
        for (int h = 0; h < NH; ++h) acc[h] = 0.f;
#pragma unroll 4
        for (int u = 0; u < HS; ++u) {
            float hu = fast_tanh(sSt[u] + f0 * sWk[0][u] + f1 * sWk[1][u]
                                        + f2 * sWk[2][u] + f3 * sWk[3][u]);
#pragma unroll
            for (int h = 0; h < NH; ++h) acc[h] += hu * sWo[u * NH + h];
        }
        float* kp = kmqt + ((size_t)s * NT + t) * NH;
#pragma unroll
        for (int h = 0; h < NH; ++h) kp[h] = __expf(acc[h] + sBo[h]);
        // forcing: vL = clip(T2 / max(T2-T1, 1e-6), 0, 1)
        float denom = fmaxf(f1 - f0, 1e-6f);
        float vL = fminf(fmaxf(f1 * fast_rcp(denom), 0.f), 1.f);
        float pl = p0 * vL;
        size_t o = (size_t)s * NT + t;
        psplev[0 * (size_t)NS * NT + o] = p0 - pl;  // Ps (snow)
        psplev[1 * (size_t)NS * NT + o] = pl;       // Pl (liquid)
        psplev[2 * (size_t)NS * NT + o] = p1;       // Ev
    }
}

// ---------------------------------------------------------------------------
// Kernel 3: sequential scan. Block = 16 sites x 16 heads. LDS-staged chunks.
// qTot overwrites km in place (same element read-then-written per thread).
// ---------------------------------------------------------------------------
__global__ __launch_bounds__(256) void k_scan(
    const float* __restrict__ params, const float* __restrict__ psplev,
    float* __restrict__ kmqt)
{
    int tid = threadIdx.x;
    int sl = tid >> 4, h = tid & 15;
    int s = blockIdx.x * 16 + sl;
    __shared__ float sKm[TC][256];      // [tc][tid] -- thread-private columns
    __shared__ float sIn[3][TC][16];    // [Ps/Pl/Ev][tc][site]
    const float* P = params + s * 128;
    float kp = P[h], ks = P[16 + h], kd = P[32 + h], gd = P[48 + h];
    float gl = P[64 + h], qb = P[80 + h], gi = P[96 + h], ge = P[112 + h];
    float gi1 = 1.f - gi, gd1 = 1.f - gd, kd1 = 1.f - kd;
    float Sf = 0.f, Ss = 0.f, Sd = 0.f;
    for (int t0 = 0; t0 < NT; t0 += TC) {
        // km chunk: each thread loads its own (s,h) column
#pragma unroll
        for (int tc = 0; tc < TC; ++tc)
            sKm[tc][tid] = kmqt[((size_t)s * NT + t0 + tc) * NH + h];
        // forcing chunk (cross-thread)
        for (int idx = tid; idx < 3 * 16 * TC; idx += 256) {
            int row = idx / TC;
            int tc = idx - row * TC;
            int a = row >> 4, ssl = row & 15;
            sIn[a][tc][ssl] =
                psplev[(size_t)a * NS * NT + (size_t)(blockIdx.x * 16 + ssl) * NT + t0 + tc];
        }
        __syncthreads();
#pragma unroll 8
        for (int tc = 0; tc < TC; ++tc) {
            float ps = sIn[0][tc][sl], pl = sIn[1][tc][sl], ev = sIn[2][tc][sl];
            float kmv = sKm[tc][tid];
            Sf += ps;
            float qf = fminf(Sf, kmv);
            Sf -= qf;
            float Pin = pl + qf;
            float H = fmaxf(Ss + Pin * gi1 - ev * ge, 0.f);
            float qp = fmaxf(H - gl, 0.f) * kp;
            float qo = fminf(H, gl) * ks;
            Ss = H - qp - qo;
            float D = Sd + Pin * gi + qo * gd;
            float qd = D * kd + qb;
            Sd = D * kd1;
            sKm[tc][tid] = qp + qo * gd1 + qd;  // qTot
        }
        // dump qTot (thread-private column, no barrier needed before this)
#pragma unroll
        for (int tc = 0; tc < TC; ++tc)
            kmqt[((size_t)s * NT + t0 + tc) * NH + h] = sKm[tc][tid];
        __syncthreads();  // protect sIn WAR for next chunk
    }
}

// ---------------------------------------------------------------------------
// Kernel 4: FIR readout. Block per site; whole qTot[s] transposed into LDS.
// Thread handles tau in {tid, tid+256, tid+512, tid+768} -> conflict-free reads.
// ---------------------------------------------------------------------------
__global__ __launch_bounds__(256) void k_fir(
    const float* __restrict__ kmqt /* qTot */, const float* __restrict__ wfir,
    float* __restrict__ out)
{
    int s = blockIdx.x, tid = threadIdx.x;
    __shared__ float sQ[NH * NT];   // sQ[h*NT + t]
    __shared__ float sW[NR * NH];   // sW[i*16 + h]
    for (int idx = tid; idx < NH * NT; idx += 256) {
        int t = idx >> 4, h = idx & 15;
        sQ[h * NT + t] = kmqt[(size_t)s * NT * NH + idx];
    }
    if (tid < NR * NH) sW[tid] = wfir[s * NR * NH + tid];
    __syncthreads();
#pragma unroll
    for (int c = 0; c < 4; ++c) {
        int tau = tid + 256 * c;
        if (tau < LOUT) {
            float acc = 0.f;
#pragma unroll
            for (int h = 0; h < NH; ++h) {
                const float* q = sQ + h * NT + tau;
#pragma unroll
                for (int i = 0; i < NR; ++i) acc += q[i] * sW[i * 16 + h];
            }
            out[(size_t)tau * NS + s] = acc;
        }
    }
}

// ---------------------------------------------------------------------------
extern "C" void kernel_launch(void* const* d_in, const int* in_sizes, int n_in,
                              void* d_out, int out_size, void* d_ws, size_t ws_size,
                              hipStream_t stream) {
    const float* x      = (const float*)d_in[0];
    const float* xc     = (const float*)d_in[1];
    const float* W_fc   = (const float*)d_in[2];
    const float* b_fc   = (const float*)d_in[3];
    const float* W_r    = (const float*)d_in[4];
    const float* b_r    = (const float*)d_in[5];
    const float* W_g    = (const float*)d_in[6];
    const float* b_g    = (const float*)d_in[7];
    const float* W_kin  = (const float*)d_in[8];
    const float* b_kin  = (const float*)d_in[9];
    const float* W_kout = (const float*)d_in[10];
    const float* b_kout = (const float*)d_in[11];
    float* out = (float*)d_out;

    float* ws     = (float*)d_ws;
    float* state2 = ws;                            // NS*HS            = 512,000
    float* params = state2 + (size_t)NS * HS;      // NS*8*NH          = 256,000
    float* wfir   = params + (size_t)NS * 8 * NH;  // NS*NR*NH         = 480,000
    float* psplev = wfir + (size_t)NS * NR * NH;   // 3*NS*NT          = 6,000,000
    float* kmqt   = psplev + (size_t)3 * NS * NT;  // NS*NT*NH         = 32,000,000
    // total ~157 MB of workspace

    k_site<<<NS, 256, 0, stream>>>(xc, W_fc, b_fc, W_r, b_r, W_g, b_g, b_kin,
                                   state2, params, wfir);
    k_km<<<NS, 256, 0, stream>>>(x, state2, W_kin, W_kout, b_kout, kmqt, psplev);
    k_scan<<<NS / 16, 256, 0, stream>>>(params, psplev, kmqt);
    k_fir<<<NS, 256, 0, stream>>>(kmqt, wfir, out);
}

// Round 2
// 621.517 us; speedup vs baseline: 1.0576x; 1.0576x over previous
//
#include <hip/hip_runtime.h>
#include <hip/hip_bf16.h>

#define NG 32
#define NH 16
#define NR 15
#define HS 256
#define NT 1000
#define NS 2000
#define LOUT (NT - NR + 1)  // 986
#define TC 40               // scan time-chunk

typedef __attribute__((ext_vector_type(8))) short bhalf8;
typedef __attribute__((ext_vector_type(4))) float f32x4;

__device__ __forceinline__ float fast_rcp(float x) { return __builtin_amdgcn_rcpf(x); }
__device__ __forceinline__ float fast_tanh(float x) {
    float e = __expf(2.0f * x);
    return 1.0f - 2.0f * fast_rcp(e + 1.0f);
}
__device__ __forceinline__ float fast_sigmoid(float x) {
    return fast_rcp(1.0f + __expf(-x));
}
__device__ __forceinline__ short f2bf(float f) {
    __bf16 h = (__bf16)f;
    return __builtin_bit_cast(short, h);
}
// tanh with pre-scaled input: x already multiplied by 2*log2(e)
__device__ __forceinline__ float tanh_scaled(float x) {
    float e = __builtin_amdgcn_exp2f(x);
    return 1.0f - 2.0f * fast_rcp(e + 1.0f);
}

// ---------------------------------------------------------------------------
// Kernel 1: per-site parameters. One block per site, 256 threads (= HS).
// ---------------------------------------------------------------------------
__global__ __launch_bounds__(256) void k_site(
    const float* __restrict__ xc, const float* __restrict__ W_fc, const float* __restrict__ b_fc,
    const float* __restrict__ W_r, const float* __restrict__ b_r,
    const float* __restrict__ W_g, const float* __restrict__ b_g,
    const float* __restrict__ b_kin,
    float* __restrict__ state2, float* __restrict__ params, float* __restrict__ wfir)
{
    int s = blockIdx.x, tid = threadIdx.x;
    __shared__ float sXc[NG];
    __shared__ float sG[HS];
    __shared__ float sPG[144];
    __shared__ float sPR[256];
    if (tid < NG) sXc[tid] = xc[s * NG + tid];
    __syncthreads();
    float st = b_fc[tid];
#pragma unroll
    for (int g = 0; g < NG; ++g) st += sXc[g] * W_fc[g * HS + tid];
    state2[s * HS + tid] = st + b_kin[tid];
    float gv = fast_tanh(st);
    sG[tid] = gv;
    __syncthreads();
    {
        float a = b_r[tid];
#pragma unroll 8
        for (int u = 0; u < HS; ++u) a += sG[u] * W_r[u * 256 + tid];
        sPR[tid] = a;
    }
    if (tid < 144) {
        float a = b_g[tid];
#pragma unroll 8
        for (int u = 0; u < HS; ++u) a += sG[u] * W_g[u * 144 + tid];
        sPG[tid] = a;
    }
    __syncthreads();
    if (tid < NH) {
        int h = tid;
        float m = -1e30f;
        for (int k = 0; k < NH; ++k) m = fmaxf(m, sPG[96 + k]);
        float sum = 0.f;
        for (int k = 0; k < NH; ++k) sum += __expf(sPG[96 + k] - m);
        float ga = __expf(sPG[96 + h] - m) * fast_rcp(sum);
        float kp = fast_sigmoid(sPG[h]);
        float ks = fast_sigmoid(sPG[16 + h]);
        float kd = fast_sigmoid(sPG[32 + h]);
        float gd = fast_sigmoid(sPG[48 + h]);
        float glv = fast_sigmoid(sPG[64 + h]) * 10.0f;
        float gl = glv * glv * glv;
        float qb = fmaxf(sPG[80 + h], 0.f) * 0.1f;
        float gi = fminf(fmaxf(sPG[112 + h] * (1.0f / 6.0f) + 0.5f, 0.f), 1.f) * 0.5f;
        float ge = fmaxf(sPG[128 + h], 0.f);
        float* P = params + s * 128;
        P[0 * 16 + h] = kp;  P[1 * 16 + h] = ks;  P[2 * 16 + h] = kd;  P[3 * 16 + h] = gd;
        P[4 * 16 + h] = gl;  P[5 * 16 + h] = qb;  P[6 * 16 + h] = gi;  P[7 * 16 + h] = ge;
        float loc = fast_sigmoid(sPR[h * 16 + 0]) * 15.0f;
        float l[NR];
        float mm = -1e30f;
#pragma unroll
        for (int i = 0; i < NR; ++i) {
            float d = (float)i - loc;
            l[i] = sPR[h * 16 + 1 + i] - d * d;
            mm = fmaxf(mm, l[i]);
        }
        float ssum = 0.f;
#pragma unroll
        for (int i = 0; i < NR; ++i) { l[i] = __expf(l[i] - mm); ssum += l[i]; }
        float r = fast_rcp(ssum) * ga;
#pragma unroll
        for (int i = 0; i < NR; ++i) wfir[s * (NR * NH) + i * NH + h] = l[i] * r;
    }
}

// ---------------------------------------------------------------------------
// Kernel 2 (MFMA): km[s,t,h] = exp(tanh(state2 + f·W_kin) @ W_kout + b_kout).
// One block per site, 4 waves. Each wave: 16(t)x16(h) output tile via
// mfma_f32_16x16x32_bf16 over 8 K-chunks of HS=256.
// A-frag: row(t)=lane&15, k(u)=(lane>>4)*8+e.  B-frag: col(h)=lane&15, same k.
// C/D: col(h)=lane&15, row(t)=(lane>>4)*4+reg  [m89-verified layout].
// Also produces forcing (Ps,Pl,Ev) transposed to [s][t].
// ---------------------------------------------------------------------------
__global__ __launch_bounds__(256) void k_km(
    const float* __restrict__ x, const float* __restrict__ state2,
    const float* __restrict__ W_kin, const float* __restrict__ W_kout,
    const float* __restrict__ b_kout,
    float* __restrict__ kmqt, float* __restrict__ psplev)
{
    const float Ck = 2.8853900817779268f;  // 2*log2(e)
    int s = blockIdx.x, tid = threadIdx.x;
    __shared__ float sSt[HS], sW0[HS], sW1[HS], sW2[HS], sW3[HS];
    sSt[tid] = state2[s * HS + tid] * Ck;
    sW0[tid] = W_kin[0 * HS + tid] * Ck;
    sW1[tid] = W_kin[1 * HS + tid] * Ck;
    sW2[tid] = W_kin[2 * HS + tid] * Ck;
    sW3[tid] = W_kin[3 * HS + tid] * Ck;

    // forcing precompute (global-only, overlaps LDS staging)
    for (int t = tid; t < NT; t += 256) {
        const float* xp = x + ((size_t)t * NS + s) * 6;
        float2 pe = *(const float2*)xp;        // Prcp, Evp
        float2 tt = *(const float2*)(xp + 2);  // T1, T2
        float denom = fmaxf(tt.y - tt.x, 1e-6f);
        float vL = fminf(fmaxf(tt.y * fast_rcp(denom), 0.f), 1.f);
        float pl = pe.x * vL;
        size_t o = (size_t)s * NT + t;
        psplev[o] = pe.x - pl;
        psplev[(size_t)NS * NT + o] = pl;
        psplev[2 * (size_t)NS * NT + o] = pe.y;
    }
    __syncthreads();

    int wave = tid >> 6, lane = tid & 63;
    int r15 = lane & 15;       // A-row (t) during load; output column (h) in epilogue
    int kg = lane >> 4;        // k-group during load; output row-block in epilogue

    // W_kout B-fragments, loop-invariant: 8 chunks x 8 bf16 = 32 VGPRs
    bhalf8 Bf[8];
#pragma unroll
    for (int kc = 0; kc < 8; ++kc) {
        int u0 = kc * 32 + kg * 8;
#pragma unroll
        for (int e = 0; e < 8; ++e)
            Bf[kc][e] = f2bf(W_kout[(u0 + e) * NH + r15]);
    }
    float bk = b_kout[r15];

    for (int tb = wave * 16; tb < NT; tb += 64) {
        int t = tb + r15;
        int tcl = t < NT ? t : NT - 1;
        const float* xp = x + ((size_t)tcl * NS + s) * 6;
        float2 fa = *(const float2*)(xp + 2);
        float2 fb = *(const float2*)(xp + 4);
        float f0 = fa.x, f1 = fa.y, f2 = fb.x, f3 = fb.y;
        f32x4 acc = {0.f, 0.f, 0.f, 0.f};
#pragma unroll
        for (int kc = 0; kc < 8; ++kc) {
            int u0 = kc * 32 + kg * 8;
            bhalf8 A;
#pragma unroll
            for (int half = 0; half < 2; ++half) {
                int ub = u0 + 4 * half;
                float4 sv = *(const float4*)&sSt[ub];
                float4 w0 = *(const float4*)&sW0[ub];
                float4 w1 = *(const float4*)&sW1[ub];
                float4 w2 = *(const float4*)&sW2[ub];
                float4 w3 = *(const float4*)&sW3[ub];
                float p0 = sv.x + f0 * w0.x + f1 * w1.x + f2 * w2.x + f3 * w3.x;
                float p1 = sv.y + f0 * w0.y + f1 * w1.y + f2 * w2.y + f3 * w3.y;
                float p2 = sv.z + f0 * w0.z + f1 * w1.z + f2 * w2.z + f3 * w3.z;
                float p3 = sv.w + f0 * w0.w + f1 * w1.w + f2 * w2.w + f3 * w3.w;
                A[4 * half + 0] = f2bf(tanh_scaled(p0));
                A[4 * half + 1] = f2bf(tanh_scaled(p1));
                A[4 * half + 2] = f2bf(tanh_scaled(p2));
                A[4 * half + 3] = f2bf(tanh_scaled(p3));
            }
            acc = __builtin_amdgcn_mfma_f32_16x16x32_bf16(A, Bf[kc], acc, 0, 0, 0);
        }
        // epilogue: lane holds D[t=tb+kg*4+j][h=r15]
        float* kp = kmqt + (size_t)s * NT * NH;
#pragma unroll
        for (int j = 0; j < 4; ++j) {
            int tt = tb + kg * 4 + j;
            if (tt < NT) kp[(size_t)tt * NH + r15] = __expf(acc[j] + bk);
        }
    }
}

// ---------------------------------------------------------------------------
// Kernel 3: sequential scan. Block = 16 sites x 16 heads. LDS-staged chunks.
// qTot overwrites km in place (same element read-then-written per thread).
// ---------------------------------------------------------------------------
__global__ __launch_bounds__(256) void k_scan(
    const float* __restrict__ params, const float* __restrict__ psplev,
    float* __restrict__ kmqt)
{
    int tid = threadIdx.x;
    int sl = tid >> 4, h = tid & 15;
    int s = blockIdx.x * 16 + sl;
    __shared__ float sKm[TC][256];
    __shared__ float sIn[3][TC][16];
    const float* P = params + s * 128;
    float kp = P[h], ks = P[16 + h], kd = P[32 + h], gd = P[48 + h];
    float gl = P[64 + h], qb = P[80 + h], gi = P[96 + h], ge = P[112 + h];
    float gi1 = 1.f - gi, gd1 = 1.f - gd, kd1 = 1.f - kd;
    float Sf = 0.f, Ss = 0.f, Sd = 0.f;
    for (int t0 = 0; t0 < NT; t0 += TC) {
#pragma unroll
        for (int tc = 0; tc < TC; ++tc)
            sKm[tc][tid] = kmqt[((size_t)s * NT + t0 + tc) * NH + h];
        for (int idx = tid; idx < 3 * 16 * TC; idx += 256) {
            int row = idx / TC;
            int tc = idx - row * TC;
            int a = row >> 4, ssl = row & 15;
            sIn[a][tc][ssl] =
                psplev[(size_t)a * NS * NT + (size_t)(blockIdx.x * 16 + ssl) * NT + t0 + tc];
        }
        __syncthreads();
#pragma unroll 8
        for (int tc = 0; tc < TC; ++tc) {
            float ps = sIn[0][tc][sl], pl = sIn[1][tc][sl], ev = sIn[2][tc][sl];
            float kmv = sKm[tc][tid];
            Sf += ps;
            float qf = fminf(Sf, kmv);
            Sf -= qf;
            float Pin = pl + qf;
            float H = fmaxf(Ss + Pin * gi1 - ev * ge, 0.f);
            float qp = fmaxf(H - gl, 0.f) * kp;
            float qo = fminf(H, gl) * ks;
            Ss = H - qp - qo;
            float D = Sd + Pin * gi + qo * gd;
            float qd = D * kd + qb;
            Sd = D * kd1;
            sKm[tc][tid] = qp + qo * gd1 + qd;
        }
#pragma unroll
        for (int tc = 0; tc < TC; ++tc)
            kmqt[((size_t)s * NT + t0 + tc) * NH + h] = sKm[tc][tid];
        __syncthreads();
    }
}

// ---------------------------------------------------------------------------
// Kernel 4: FIR readout. Block per site; whole qTot[s] transposed into LDS.
// ---------------------------------------------------------------------------
__global__ __launch_bounds__(256) void k_fir(
    const float* __restrict__ kmqt, const float* __restrict__ wfir,
    float* __restrict__ out)
{
    int s = blockIdx.x, tid = threadIdx.x;
    __shared__ float sQ[NH * NT];
    __shared__ float sW[NR * NH];
    for (int idx = tid; idx < NH * NT; idx += 256) {
        int t = idx >> 4, h = idx & 15;
        sQ[h * NT + t] = kmqt[(size_t)s * NT * NH + idx];
    }
    if (tid < NR * NH) sW[tid] = wfir[s * NR * NH + tid];
    __syncthreads();
#pragma unroll
    for (int c = 0; c < 4; ++c) {
        int tau = tid + 256 * c;
        if (tau < LOUT) {
            float acc = 0.f;
#pragma unroll
            for (int h = 0; h < NH; ++h) {
                const float* q = sQ + h * NT + tau;
#pragma unroll
                for (int i = 0; i < NR; ++i) acc += q[i] * sW[i * 16 + h];
            }
            out[(size_t)tau * NS + s] = acc;
        }
    }
}

// ---------------------------------------------------------------------------
extern "C" void kernel_launch(void* const* d_in, const int* in_sizes, int n_in,
                              void* d_out, int out_size, void* d_ws, size_t ws_size,
                              hipStream_t stream) {
    const float* x      = (const float*)d_in[0];
    const float* xc     = (const float*)d_in[1];
    const float* W_fc   = (const float*)d_in[2];
    const float* b_fc   = (const float*)d_in[3];
    const float* W_r    = (const float*)d_in[4];
    const float* b_r    = (const float*)d_in[5];
    const float* W_g    = (const float*)d_in[6];
    const float* b_g    = (const float*)d_in[7];
    const float* W_kin  = (const float*)d_in[8];
    const float* b_kin  = (const float*)d_in[9];
    const float* W_kout = (const float*)d_in[10];
    const float* b_kout = (const float*)d_in[11];
    float* out = (float*)d_out;

    float* ws     = (float*)d_ws;
    float* state2 = ws;                            // NS*HS
    float* params = state2 + (size_t)NS * HS;      // NS*8*NH
    float* wfir   = params + (size_t)NS * 8 * NH;  // NS*NR*NH
    float* psplev = wfir + (size_t)NS * NR * NH;   // 3*NS*NT
    float* kmqt   = psplev + (size_t)3 * NS * NT;  // NS*NT*NH

    k_site<<<NS, 256, 0, stream>>>(xc, W_fc, b_fc, W_r, b_r, W_g, b_g, b_kin,
                                   state2, params, wfir);
    k_km<<<NS, 256, 0, stream>>>(x, state2, W_kin, W_kout, b_kout, kmqt, psplev);
    k_scan<<<NS / 16, 256, 0, stream>>>(params, psplev, kmqt);
    k_fir<<<NS, 256, 0, stream>>>(kmqt, wfir, out);
}